// Round 9
// baseline (453.092 us; speedup 1.0000x reference)
//
#include <hip/hip_runtime.h>
#include <hip/hip_bf16.h>

#define LL 4
#define NN 50000
#define DD 64
#define EE 500000
#define HID 256
#define KDIM 512
#define LN_EPS 1e-5f

typedef __bf16 bf16x8 __attribute__((ext_vector_type(8)));
typedef float f32x16 __attribute__((ext_vector_type(16)));

__device__ __forceinline__ void async16(const void* g, void* l) {
    __builtin_amdgcn_global_load_lds(
        (const __attribute__((address_space(1))) void*)g,
        (__attribute__((address_space(3))) void*)l, 16, 0, 0);
}

// ---------- kernel 1: W1 (256x512 f32) -> W'' (512 out-cols x 256 K) bf16 ----
// Out-col j<256: Ps row j (src cols of W1); j>=256: Pd row j-256 (dst cols).
// K index k means feature (l = k>>6, d = k&63) -> W1 col l*128 + 64*(j>=256) + d.
// Chunk layout: w2c[(b*512 + j)*8 + z], chunk b covers k in [8b, 8b+8).
__global__ void w2_conv(const float* __restrict__ w1, __bf16* __restrict__ o) {
    int t = blockIdx.x * 256 + threadIdx.x;                 // 16384 threads
    int j  = t & 511;
    int b  = t >> 9;              // [0,32)
    int k0 = (b >> 1) * 16 + (b & 1) * 8;                   // == 8*b
    int r  = j & 255;
    int col = (k0 >> 6) * 128 + ((j >> 8) ? 64 : 0) + (k0 & 63);
    const float4* p = (const float4*)(w1 + r * KDIM + col);
    float4 va = p[0];
    float4 vb = p[1];
    bf16x8 v;
    v[0] = (__bf16)va.x; v[1] = (__bf16)va.y; v[2] = (__bf16)va.z; v[3] = (__bf16)va.w;
    v[4] = (__bf16)vb.x; v[5] = (__bf16)vb.y; v[6] = (__bf16)vb.z; v[7] = (__bf16)vb.w;
    *(bf16x8*)(o + (size_t)t * 8) = v;
}

// ---------- kernel 2: FUSED tanh + node projections (R6 structure) ----------
// P[n][512] = [Ps | Pd+b1] (bf16). Grid 391. Measured-best node_proj
// (totals 195.1/194.4 in R6/R8). R7's 8-phase/direct-store variant regressed
// +24 us (scalar 2B stores + 2x barriers). Keep the coalesced LDS bounce.
__global__ __launch_bounds__(256, 2)
void node_proj(const float* __restrict__ h, const __bf16* __restrict__ w2c,
               const float* __restrict__ b1, __bf16* __restrict__ P) {
    __shared__ __align__(16) char smem[65536];
    __bf16* Bs  = (__bf16*)smem;      // 64 KB B slice during MFMA
    __bf16* Cs2 = (__bf16*)smem;      // 32 KB bf16 C bounce (phase-separated)

    const int tid  = threadIdx.x;
    const int wave = tid >> 6;
    const int lane = tid & 63;
    const int h32  = lane >> 5;
    const int c32  = lane & 31;
    const int n00  = blockIdx.x * 128;

    // stage B slice for cb=0: 16 x 2KB linear pieces
    #pragma unroll
    for (int it = 0; it < 16; ++it) {
        int o = it * 2048 + tid * 8;   // elem offset within 32768-elem slice
        async16(w2c + (size_t)(o >> 10) * 4096 + (o & 1023), Bs + o);
    }

    // A fragments: read h (f32) once, tanh+scale+convert in registers.
    // frag u: l = u>>2, k-chunk = (u&3)*16 + h32*8, m = c32 -> node.
    int node = n00 + wave * 32 + c32;
    if (node >= NN) node = NN - 1;
    bf16x8 af[16];
    #pragma unroll
    for (int u = 0; u < 16; ++u) {
        int l = u >> 2;
        float imp = (float)(l + 1) * 0.1f;
        const float* p = h + (size_t)l * (NN * DD) + node * DD
                       + (u & 3) * 16 + h32 * 8;
        float4 va = *(const float4*)p;
        float4 vb = *(const float4*)(p + 4);
        float xv[8] = {va.x, va.y, va.z, va.w, vb.x, vb.y, vb.z, vb.w};
        #pragma unroll
        for (int z = 0; z < 8; ++z) {
            float e2 = __expf(2.0f * (imp * xv[z]));
            af[u][z] = (__bf16)(1.0f - 2.0f / (e2 + 1.0f));
        }
    }

    for (int cb = 0; cb < 4; ++cb) {
        __syncthreads();               // B(cb) resident; LDS free of prior phase

        f32x16 acc[4];
        #pragma unroll
        for (int nt = 0; nt < 4; ++nt) acc[nt] = (f32x16)(0.f);

        #pragma unroll
        for (int u = 0; u < 16; ++u) {
            const __bf16* Bk = Bs + (u * 2 + h32) * 1024 + c32 * 8;
            #pragma unroll
            for (int nt = 0; nt < 4; ++nt) {
                bf16x8 bf = *(const bf16x8*)(Bk + nt * 256);
                acc[nt] = __builtin_amdgcn_mfma_f32_32x32x16_bf16(af[u], bf, acc[nt], 0, 0, 0);
            }
        }
        __syncthreads();               // all waves done reading Bs

        // b1 fold for dst half (cols 256..511): col = cb*128 + nt*32 + c32
        float b1v[4];
        #pragma unroll
        for (int nt = 0; nt < 4; ++nt)
            b1v[nt] = (cb >= 2) ? b1[(cb - 2) * 128 + nt * 32 + c32] : 0.f;

        // bounce C (bf16) through LDS for coalesced row stores
        // C/D 32x32 layout: col = c32, row = (r&3) + 8*(r>>2) + 4*h32
        #pragma unroll
        for (int nt = 0; nt < 4; ++nt) {
            #pragma unroll
            for (int r = 0; r < 16; ++r) {
                int nl = wave * 32 + (r & 3) + 8 * (r >> 2) + 4 * h32;
                Cs2[nl * 128 + nt * 32 + c32] = (__bf16)(acc[nt][r] + b1v[nt]);
            }
        }
        __syncthreads();               // Cs2 complete

        #pragma unroll
        for (int it = 0; it < 8; ++it) {
            int o  = it * 2048 + tid * 8;
            int nl = o >> 7;
            int n  = n00 + nl;
            if (n < NN)
                *(bf16x8*)(P + (size_t)n * 512 + cb * 128 + (o & 127)) =
                    *(const bf16x8*)(Cs2 + o);
        }

        if (cb < 3) {
            __syncthreads();           // store-side LDS reads done before overwrite
            #pragma unroll
            for (int it = 0; it < 16; ++it) {
                int o = it * 2048 + tid * 8;
                async16(w2c + (size_t)(o >> 10) * 4096 + (cb + 1) * 1024 + (o & 1023),
                        Bs + o);
            }
        }
    }
}

// ---------- kernel 3: per-edge gather + LN + ReLU + dot ---------------------
// R9 single-knob experiment: __launch_bounds__(256,3) -> (256,8).
// Rationale: occupancy has tracked the declared bound across all rounds
// ((256,3)->36-37%, (256,2)->18.7%) while VGPR=60 permits 8 waves/SIMD.
// The kernel is latency-bound (HBM 43%, L2 ~21%, VALU 53% -- nothing
// saturated); resident waves directly multiply outstanding gather requests.
// Everything else byte-identical to the measured-best R8 build.
__global__ __launch_bounds__(256, 8)
void edge_out(const __bf16* __restrict__ P, const int* __restrict__ src,
              const int* __restrict__ dst,
              const float* __restrict__ w3, const float* __restrict__ b3,
              const float* __restrict__ gamma, const float* __restrict__ beta,
              float* __restrict__ out) {
    const int tid = threadIdx.x;
    const int g   = tid >> 4;
    const int j   = tid & 15;

    float gv[16], btv[16], wv[16];
    {
        const float4* pg = (const float4*)(gamma + j * 16);
        const float4* pt = (const float4*)(beta + j * 16);
        const float4* pw = (const float4*)(w3 + j * 16);
        #pragma unroll
        for (int z = 0; z < 4; ++z) {
            float4 vg = pg[z], vt = pt[z], vw = pw[z];
            gv [z*4+0] = vg.x; gv [z*4+1] = vg.y; gv [z*4+2] = vg.z; gv [z*4+3] = vg.w;
            btv[z*4+0] = vt.x; btv[z*4+1] = vt.y; btv[z*4+2] = vt.z; btv[z*4+3] = vt.w;
            wv [z*4+0] = vw.x; wv [z*4+1] = vw.y; wv [z*4+2] = vw.z; wv [z*4+3] = vw.w;
        }
    }
    const float b3v = b3[0];
    const int e0 = blockIdx.x * 128 + g * 8;

    // preload this group's 8 src + 8 dst indices (lane j&7 holds edge e0+(j&7))
    int ep = e0 + (j & 7);
    if (ep >= EE) ep = EE - 1;
    const int sj = src[ep];
    const int dj = dst[ep];

    uint4 s0[3], s1[3], d0[3], d1[3];   // 3-slot rotation, static indices

    #pragma unroll
    for (int i = 0; i < 2; ++i) {       // prologue: edges 0 and 1 in flight
        int s = __shfl(sj, i, 16);
        int d = __shfl(dj, i, 16);
        const uint4* ps = (const uint4*)(P + (size_t)s * 512 + j * 16);
        const uint4* pd = (const uint4*)(P + (size_t)d * 512 + 256 + j * 16);
        s0[i] = ps[0]; s1[i] = ps[1]; d0[i] = pd[0]; d1[i] = pd[1];
    }

    #pragma unroll
    for (int i = 0; i < 8; ++i) {
        if (i + 2 < 8) {                // prefetch edge i+2
            const int slot = (i + 2) % 3;
            int s = __shfl(sj, i + 2, 16);
            int d = __shfl(dj, i + 2, 16);
            const uint4* ps = (const uint4*)(P + (size_t)s * 512 + j * 16);
            const uint4* pd = (const uint4*)(P + (size_t)d * 512 + 256 + j * 16);
            s0[slot] = ps[0]; s1[slot] = ps[1]; d0[slot] = pd[0]; d1[slot] = pd[1];
        }
        const int cs = i % 3;
        bf16x8 a0 = __builtin_bit_cast(bf16x8, s0[cs]);
        bf16x8 a1 = __builtin_bit_cast(bf16x8, s1[cs]);
        bf16x8 c0 = __builtin_bit_cast(bf16x8, d0[cs]);
        bf16x8 c1 = __builtin_bit_cast(bf16x8, d1[cs]);
        float x[16];
        #pragma unroll
        for (int z = 0; z < 8; ++z) {
            x[z]     = (float)a0[z] + (float)c0[z];     // b1 already folded in P
            x[z + 8] = (float)a1[z] + (float)c1[z];
        }
        float sum = 0.f, sq = 0.f;
        #pragma unroll
        for (int z = 0; z < 16; ++z) {
            sum += x[z];
            sq   = fmaf(x[z], x[z], sq);
        }
        #pragma unroll
        for (int m = 1; m < 16; m <<= 1) {
            sum += __shfl_xor(sum, m);
            sq  += __shfl_xor(sq,  m);
        }
        float mu = sum * (1.0f / 256.0f);
        float rs = rsqrtf(sq * (1.0f / 256.0f) - mu * mu + LN_EPS);
        float dot = 0.f;
        #pragma unroll
        for (int z = 0; z < 16; ++z) {
            float y = fmaxf((x[z] - mu) * rs * gv[z] + btv[z], 0.f);
            dot = fmaf(y, wv[z], dot);
        }
        #pragma unroll
        for (int m = 1; m < 16; m <<= 1) dot += __shfl_xor(dot, m);
        int e = e0 + i;
        if (j == 0 && e < EE) out[e] = dot + b3v;
    }

    // keep-alive (matches the measured-best build exactly)
    #pragma unroll
    for (int z = 0; z < 16; ++z)
        asm volatile("" :: "v"(gv[z]), "v"(btv[z]), "v"(wv[z]));
}

extern "C" void kernel_launch(void* const* d_in, const int* in_sizes, int n_in,
                              void* d_out, int out_size, void* d_ws, size_t ws_size,
                              hipStream_t stream) {
    const float* h_all  = (const float*)d_in[0];
    const int*   src    = (const int*)  d_in[1];
    const int*   dst    = (const int*)  d_in[2];
    const float* W1     = (const float*)d_in[3];
    const float* b1     = (const float*)d_in[4];
    const float* W3     = (const float*)d_in[5];
    const float* b3     = (const float*)d_in[6];
    const float* gamma2 = (const float*)d_in[7];
    const float* beta2  = (const float*)d_in[8];
    float* out = (float*)d_out;

    __bf16* w2c = (__bf16*)d_ws;                       // 131072 bf16 = 256 KB
    __bf16* P   = w2c + 131072;                        // 50000*512 bf16 = 51.2 MB

    w2_conv<<<64, 256, 0, stream>>>(W1, w2c);
    node_proj<<<(NN + 127) / 128, 256, 0, stream>>>(h_all, w2c, b1, P);
    edge_out<<<(EE + 127) / 128, 256, 0, stream>>>(P, src, dst, W3, b3,
                                                   gamma2, beta2, out);
}

// Round 10
// 351.493 us; speedup vs baseline: 1.2890x; 1.2890x over previous
//
#include <hip/hip_runtime.h>
#include <hip/hip_bf16.h>

#define LL 4
#define NN 50000
#define DD 64
#define EE 500000
#define HID 256
#define KDIM 512
#define LN_EPS 1e-5f

typedef __bf16 bf16x8 __attribute__((ext_vector_type(8)));
typedef float f32x16 __attribute__((ext_vector_type(16)));

__device__ __forceinline__ void async16(const void* g, void* l) {
    __builtin_amdgcn_global_load_lds(
        (const __attribute__((address_space(1))) void*)g,
        (__attribute__((address_space(3))) void*)l, 16, 0, 0);
}

// ---------- kernel 1: W1 (256x512 f32) -> W'' (512 out-cols x 256 K) bf16 ----
// Out-col j<256: Ps row j (src cols of W1); j>=256: Pd row j-256 (dst cols).
// K index k means feature (l = k>>6, d = k&63) -> W1 col l*128 + 64*(j>=256) + d.
// Chunk layout: w2c[(b*512 + j)*8 + z], chunk b covers k in [8b, 8b+8).
__global__ void w2_conv(const float* __restrict__ w1, __bf16* __restrict__ o) {
    int t = blockIdx.x * 256 + threadIdx.x;                 // 16384 threads
    int j  = t & 511;
    int b  = t >> 9;              // [0,32)
    int k0 = (b >> 1) * 16 + (b & 1) * 8;                   // == 8*b
    int r  = j & 255;
    int col = (k0 >> 6) * 128 + ((j >> 8) ? 64 : 0) + (k0 & 63);
    const float4* p = (const float4*)(w1 + r * KDIM + col);
    float4 va = p[0];
    float4 vb = p[1];
    bf16x8 v;
    v[0] = (__bf16)va.x; v[1] = (__bf16)va.y; v[2] = (__bf16)va.z; v[3] = (__bf16)va.w;
    v[4] = (__bf16)vb.x; v[5] = (__bf16)vb.y; v[6] = (__bf16)vb.z; v[7] = (__bf16)vb.w;
    *(bf16x8*)(o + (size_t)t * 8) = v;
}

// ---------- kernel 2: FUSED tanh + node projections (R6 structure) ----------
// P[n][512] = [Ps | Pd+b1] (bf16). Grid 391. Measured-best node_proj
// (totals 195.1/194.4 in R6/R8). R7's 8-phase/direct-store variant regressed
// +24 us (scalar 2B stores + 2x barriers). Keep the coalesced LDS bounce.
__global__ __launch_bounds__(256, 2)
void node_proj(const float* __restrict__ h, const __bf16* __restrict__ w2c,
               const float* __restrict__ b1, __bf16* __restrict__ P) {
    __shared__ __align__(16) char smem[65536];
    __bf16* Bs  = (__bf16*)smem;      // 64 KB B slice during MFMA
    __bf16* Cs2 = (__bf16*)smem;      // 32 KB bf16 C bounce (phase-separated)

    const int tid  = threadIdx.x;
    const int wave = tid >> 6;
    const int lane = tid & 63;
    const int h32  = lane >> 5;
    const int c32  = lane & 31;
    const int n00  = blockIdx.x * 128;

    // stage B slice for cb=0: 16 x 2KB linear pieces
    #pragma unroll
    for (int it = 0; it < 16; ++it) {
        int o = it * 2048 + tid * 8;   // elem offset within 32768-elem slice
        async16(w2c + (size_t)(o >> 10) * 4096 + (o & 1023), Bs + o);
    }

    // A fragments: read h (f32) once, tanh+scale+convert in registers.
    // frag u: l = u>>2, k-chunk = (u&3)*16 + h32*8, m = c32 -> node.
    int node = n00 + wave * 32 + c32;
    if (node >= NN) node = NN - 1;
    bf16x8 af[16];
    #pragma unroll
    for (int u = 0; u < 16; ++u) {
        int l = u >> 2;
        float imp = (float)(l + 1) * 0.1f;
        const float* p = h + (size_t)l * (NN * DD) + node * DD
                       + (u & 3) * 16 + h32 * 8;
        float4 va = *(const float4*)p;
        float4 vb = *(const float4*)(p + 4);
        float xv[8] = {va.x, va.y, va.z, va.w, vb.x, vb.y, vb.z, vb.w};
        #pragma unroll
        for (int z = 0; z < 8; ++z) {
            float e2 = __expf(2.0f * (imp * xv[z]));
            af[u][z] = (__bf16)(1.0f - 2.0f / (e2 + 1.0f));
        }
    }

    for (int cb = 0; cb < 4; ++cb) {
        __syncthreads();               // B(cb) resident; LDS free of prior phase

        f32x16 acc[4];
        #pragma unroll
        for (int nt = 0; nt < 4; ++nt) acc[nt] = (f32x16)(0.f);

        #pragma unroll
        for (int u = 0; u < 16; ++u) {
            const __bf16* Bk = Bs + (u * 2 + h32) * 1024 + c32 * 8;
            #pragma unroll
            for (int nt = 0; nt < 4; ++nt) {
                bf16x8 bf = *(const bf16x8*)(Bk + nt * 256);
                acc[nt] = __builtin_amdgcn_mfma_f32_32x32x16_bf16(af[u], bf, acc[nt], 0, 0, 0);
            }
        }
        __syncthreads();               // all waves done reading Bs

        // b1 fold for dst half (cols 256..511): col = cb*128 + nt*32 + c32
        float b1v[4];
        #pragma unroll
        for (int nt = 0; nt < 4; ++nt)
            b1v[nt] = (cb >= 2) ? b1[(cb - 2) * 128 + nt * 32 + c32] : 0.f;

        // bounce C (bf16) through LDS for coalesced row stores
        // C/D 32x32 layout: col = c32, row = (r&3) + 8*(r>>2) + 4*h32
        #pragma unroll
        for (int nt = 0; nt < 4; ++nt) {
            #pragma unroll
            for (int r = 0; r < 16; ++r) {
                int nl = wave * 32 + (r & 3) + 8 * (r >> 2) + 4 * h32;
                Cs2[nl * 128 + nt * 32 + c32] = (__bf16)(acc[nt][r] + b1v[nt]);
            }
        }
        __syncthreads();               // Cs2 complete

        #pragma unroll
        for (int it = 0; it < 8; ++it) {
            int o  = it * 2048 + tid * 8;
            int nl = o >> 7;
            int n  = n00 + nl;
            if (n < NN)
                *(bf16x8*)(P + (size_t)n * 512 + cb * 128 + (o & 127)) =
                    *(const bf16x8*)(Cs2 + o);
        }

        if (cb < 3) {
            __syncthreads();           // store-side LDS reads done before overwrite
            #pragma unroll
            for (int it = 0; it < 16; ++it) {
                int o = it * 2048 + tid * 8;
                async16(w2c + (size_t)(o >> 10) * 4096 + (cb + 1) * 1024 + (o & 1023),
                        Bs + o);
            }
        }
    }
}

// ---------- kernel 3: per-edge gather + LN + ReLU + dot ---------------------
// R10 single-knob: __launch_bounds__(256,6). R9's (256,8) PROVED the bound
// controls residency (occupancy 36->77%) and the memory system has headroom
// (4.3 TB/s sustained even while spilling), but the 8-wave VGPR cap (64)
// forced a 32-reg allocation -> scratch spill (FETCH 233MB->1GB). At 6
// waves/EU the cap is ~85 >= the kernel's 60 -> no spill, 75% occupancy.
// Everything else byte-identical to the measured-best R8 build.
__global__ __launch_bounds__(256, 6)
void edge_out(const __bf16* __restrict__ P, const int* __restrict__ src,
              const int* __restrict__ dst,
              const float* __restrict__ w3, const float* __restrict__ b3,
              const float* __restrict__ gamma, const float* __restrict__ beta,
              float* __restrict__ out) {
    const int tid = threadIdx.x;
    const int g   = tid >> 4;
    const int j   = tid & 15;

    float gv[16], btv[16], wv[16];
    {
        const float4* pg = (const float4*)(gamma + j * 16);
        const float4* pt = (const float4*)(beta + j * 16);
        const float4* pw = (const float4*)(w3 + j * 16);
        #pragma unroll
        for (int z = 0; z < 4; ++z) {
            float4 vg = pg[z], vt = pt[z], vw = pw[z];
            gv [z*4+0] = vg.x; gv [z*4+1] = vg.y; gv [z*4+2] = vg.z; gv [z*4+3] = vg.w;
            btv[z*4+0] = vt.x; btv[z*4+1] = vt.y; btv[z*4+2] = vt.z; btv[z*4+3] = vt.w;
            wv [z*4+0] = vw.x; wv [z*4+1] = vw.y; wv [z*4+2] = vw.z; wv [z*4+3] = vw.w;
        }
    }
    const float b3v = b3[0];
    const int e0 = blockIdx.x * 128 + g * 8;

    // preload this group's 8 src + 8 dst indices (lane j&7 holds edge e0+(j&7))
    int ep = e0 + (j & 7);
    if (ep >= EE) ep = EE - 1;
    const int sj = src[ep];
    const int dj = dst[ep];

    uint4 s0[3], s1[3], d0[3], d1[3];   // 3-slot rotation, static indices

    #pragma unroll
    for (int i = 0; i < 2; ++i) {       // prologue: edges 0 and 1 in flight
        int s = __shfl(sj, i, 16);
        int d = __shfl(dj, i, 16);
        const uint4* ps = (const uint4*)(P + (size_t)s * 512 + j * 16);
        const uint4* pd = (const uint4*)(P + (size_t)d * 512 + 256 + j * 16);
        s0[i] = ps[0]; s1[i] = ps[1]; d0[i] = pd[0]; d1[i] = pd[1];
    }

    #pragma unroll
    for (int i = 0; i < 8; ++i) {
        if (i + 2 < 8) {                // prefetch edge i+2
            const int slot = (i + 2) % 3;
            int s = __shfl(sj, i + 2, 16);
            int d = __shfl(dj, i + 2, 16);
            const uint4* ps = (const uint4*)(P + (size_t)s * 512 + j * 16);
            const uint4* pd = (const uint4*)(P + (size_t)d * 512 + 256 + j * 16);
            s0[slot] = ps[0]; s1[slot] = ps[1]; d0[slot] = pd[0]; d1[slot] = pd[1];
        }
        const int cs = i % 3;
        bf16x8 a0 = __builtin_bit_cast(bf16x8, s0[cs]);
        bf16x8 a1 = __builtin_bit_cast(bf16x8, s1[cs]);
        bf16x8 c0 = __builtin_bit_cast(bf16x8, d0[cs]);
        bf16x8 c1 = __builtin_bit_cast(bf16x8, d1[cs]);
        float x[16];
        #pragma unroll
        for (int z = 0; z < 8; ++z) {
            x[z]     = (float)a0[z] + (float)c0[z];     // b1 already folded in P
            x[z + 8] = (float)a1[z] + (float)c1[z];
        }
        float sum = 0.f, sq = 0.f;
        #pragma unroll
        for (int z = 0; z < 16; ++z) {
            sum += x[z];
            sq   = fmaf(x[z], x[z], sq);
        }
        #pragma unroll
        for (int m = 1; m < 16; m <<= 1) {
            sum += __shfl_xor(sum, m);
            sq  += __shfl_xor(sq,  m);
        }
        float mu = sum * (1.0f / 256.0f);
        float rs = rsqrtf(sq * (1.0f / 256.0f) - mu * mu + LN_EPS);
        float dot = 0.f;
        #pragma unroll
        for (int z = 0; z < 16; ++z) {
            float y = fmaxf((x[z] - mu) * rs * gv[z] + btv[z], 0.f);
            dot = fmaf(y, wv[z], dot);
        }
        #pragma unroll
        for (int m = 1; m < 16; m <<= 1) dot += __shfl_xor(dot, m);
        int e = e0 + i;
        if (j == 0 && e < EE) out[e] = dot + b3v;
    }

    // keep-alive (matches the measured-best build exactly)
    #pragma unroll
    for (int z = 0; z < 16; ++z)
        asm volatile("" :: "v"(gv[z]), "v"(btv[z]), "v"(wv[z]));
}

extern "C" void kernel_launch(void* const* d_in, const int* in_sizes, int n_in,
                              void* d_out, int out_size, void* d_ws, size_t ws_size,
                              hipStream_t stream) {
    const float* h_all  = (const float*)d_in[0];
    const int*   src    = (const int*)  d_in[1];
    const int*   dst    = (const int*)  d_in[2];
    const float* W1     = (const float*)d_in[3];
    const float* b1     = (const float*)d_in[4];
    const float* W3     = (const float*)d_in[5];
    const float* b3     = (const float*)d_in[6];
    const float* gamma2 = (const float*)d_in[7];
    const float* beta2  = (const float*)d_in[8];
    float* out = (float*)d_out;

    __bf16* w2c = (__bf16*)d_ws;                       // 131072 bf16 = 256 KB
    __bf16* P   = w2c + 131072;                        // 50000*512 bf16 = 51.2 MB

    w2_conv<<<64, 256, 0, stream>>>(W1, w2c);
    node_proj<<<(NN + 127) / 128, 256, 0, stream>>>(h_all, w2c, b1, P);
    edge_out<<<(EE + 127) / 128, 256, 0, stream>>>(P, src, dst, W3, b3,
                                                   gamma2, beta2, out);
}

// Round 11
// 202.861 us; speedup vs baseline: 2.2335x; 1.7327x over previous
//
#include <hip/hip_runtime.h>
#include <hip/hip_bf16.h>

#define LL 4
#define NN 50000
#define DD 64
#define EE 500000
#define HID 256
#define KDIM 512
#define LN_EPS 1e-5f

typedef __bf16 bf16x8 __attribute__((ext_vector_type(8)));
typedef float f32x16 __attribute__((ext_vector_type(16)));

__device__ __forceinline__ void async16(const void* g, void* l) {
    __builtin_amdgcn_global_load_lds(
        (const __attribute__((address_space(1))) void*)g,
        (__attribute__((address_space(3))) void*)l, 16, 0, 0);
}

// ---------- kernel 1: W1 (256x512 f32) -> W'' (512 out-cols x 256 K) bf16 ----
// Out-col j<256: Ps row j (src cols of W1); j>=256: Pd row j-256 (dst cols).
// K index k means feature (l = k>>6, d = k&63) -> W1 col l*128 + 64*(j>=256) + d.
// Chunk layout: w2c[(b*512 + j)*8 + z], chunk b covers k in [8b, 8b+8).
__global__ void w2_conv(const float* __restrict__ w1, __bf16* __restrict__ o) {
    int t = blockIdx.x * 256 + threadIdx.x;                 // 16384 threads
    int j  = t & 511;
    int b  = t >> 9;              // [0,32)
    int k0 = (b >> 1) * 16 + (b & 1) * 8;                   // == 8*b
    int r  = j & 255;
    int col = (k0 >> 6) * 128 + ((j >> 8) ? 64 : 0) + (k0 & 63);
    const float4* p = (const float4*)(w1 + r * KDIM + col);
    float4 va = p[0];
    float4 vb = p[1];
    bf16x8 v;
    v[0] = (__bf16)va.x; v[1] = (__bf16)va.y; v[2] = (__bf16)va.z; v[3] = (__bf16)va.w;
    v[4] = (__bf16)vb.x; v[5] = (__bf16)vb.y; v[6] = (__bf16)vb.z; v[7] = (__bf16)vb.w;
    *(bf16x8*)(o + (size_t)t * 8) = v;
}

// ---------- kernel 2: FUSED tanh + node projections (R6 structure) ----------
// P[n][512] = [Ps | Pd+b1] (bf16). Grid 391. Measured-best node_proj
// (totals 195.1/194.4 in R6/R8). Unchanged from R8.
__global__ __launch_bounds__(256, 2)
void node_proj(const float* __restrict__ h, const __bf16* __restrict__ w2c,
               const float* __restrict__ b1, __bf16* __restrict__ P) {
    __shared__ __align__(16) char smem[65536];
    __bf16* Bs  = (__bf16*)smem;      // 64 KB B slice during MFMA
    __bf16* Cs2 = (__bf16*)smem;      // 32 KB bf16 C bounce (phase-separated)

    const int tid  = threadIdx.x;
    const int wave = tid >> 6;
    const int lane = tid & 63;
    const int h32  = lane >> 5;
    const int c32  = lane & 31;
    const int n00  = blockIdx.x * 128;

    // stage B slice for cb=0: 16 x 2KB linear pieces
    #pragma unroll
    for (int it = 0; it < 16; ++it) {
        int o = it * 2048 + tid * 8;   // elem offset within 32768-elem slice
        async16(w2c + (size_t)(o >> 10) * 4096 + (o & 1023), Bs + o);
    }

    // A fragments: read h (f32) once, tanh+scale+convert in registers.
    int node = n00 + wave * 32 + c32;
    if (node >= NN) node = NN - 1;
    bf16x8 af[16];
    #pragma unroll
    for (int u = 0; u < 16; ++u) {
        int l = u >> 2;
        float imp = (float)(l + 1) * 0.1f;
        const float* p = h + (size_t)l * (NN * DD) + node * DD
                       + (u & 3) * 16 + h32 * 8;
        float4 va = *(const float4*)p;
        float4 vb = *(const float4*)(p + 4);
        float xv[8] = {va.x, va.y, va.z, va.w, vb.x, vb.y, vb.z, vb.w};
        #pragma unroll
        for (int z = 0; z < 8; ++z) {
            float e2 = __expf(2.0f * (imp * xv[z]));
            af[u][z] = (__bf16)(1.0f - 2.0f / (e2 + 1.0f));
        }
    }

    for (int cb = 0; cb < 4; ++cb) {
        __syncthreads();               // B(cb) resident; LDS free of prior phase

        f32x16 acc[4];
        #pragma unroll
        for (int nt = 0; nt < 4; ++nt) acc[nt] = (f32x16)(0.f);

        #pragma unroll
        for (int u = 0; u < 16; ++u) {
            const __bf16* Bk = Bs + (u * 2 + h32) * 1024 + c32 * 8;
            #pragma unroll
            for (int nt = 0; nt < 4; ++nt) {
                bf16x8 bf = *(const bf16x8*)(Bk + nt * 256);
                acc[nt] = __builtin_amdgcn_mfma_f32_32x32x16_bf16(af[u], bf, acc[nt], 0, 0, 0);
            }
        }
        __syncthreads();               // all waves done reading Bs

        float b1v[4];
        #pragma unroll
        for (int nt = 0; nt < 4; ++nt)
            b1v[nt] = (cb >= 2) ? b1[(cb - 2) * 128 + nt * 32 + c32] : 0.f;

        // bounce C (bf16) through LDS for coalesced row stores
        // C/D 32x32 layout: col = c32, row = (r&3) + 8*(r>>2) + 4*h32
        #pragma unroll
        for (int nt = 0; nt < 4; ++nt) {
            #pragma unroll
            for (int r = 0; r < 16; ++r) {
                int nl = wave * 32 + (r & 3) + 8 * (r >> 2) + 4 * h32;
                Cs2[nl * 128 + nt * 32 + c32] = (__bf16)(acc[nt][r] + b1v[nt]);
            }
        }
        __syncthreads();               // Cs2 complete

        #pragma unroll
        for (int it = 0; it < 8; ++it) {
            int o  = it * 2048 + tid * 8;
            int nl = o >> 7;
            int n  = n00 + nl;
            if (n < NN)
                *(bf16x8*)(P + (size_t)n * 512 + cb * 128 + (o & 127)) =
                    *(const bf16x8*)(Cs2 + o);
        }

        if (cb < 3) {
            __syncthreads();           // store-side LDS reads done before overwrite
            #pragma unroll
            for (int it = 0; it < 16; ++it) {
                int o = it * 2048 + tid * 8;
                async16(w2c + (size_t)(o >> 10) * 4096 + (cb + 1) * 1024 + (o & 1023),
                        Bs + o);
            }
        }
    }
}

// ---------- kernel 3: per-edge gather + LN + ReLU + dot (SLIM, high-occ) ----
// R11: occupancy is purchasable via launch_bounds (R9/R10 proved occupancy
// 61-77%) but the effective VGPR cap is ~256/bound (R9: 32, R10: 40) -- the
// old 60-reg kernel can't exceed bound=3 without spilling. This version is
// restructured to FIT the bound=6 cap (~40):
//  - 32-lane groups: lane j covers h = j*8..j*8+8 -> ONE uint4 per half per
//    edge (8 data regs vs 16), 512B contiguous per row half (same coalescing)
//  - no prefetch rotation (24 waves/CU of TLP replaces in-thread ILP)
//  - no const pinning (24 const values; regalloc caches or reloads from L1)
//  - rolled loop (unroll 2): minimal live set, ~30-38 regs
// Decision rule: clean counters (FETCH ~233MB, WRITE ~4.5MB) + occ ~60% +
// dur ~70 unchanged => 3.45 TB/s is the true random-gather service ceiling.
__global__ __launch_bounds__(256, 6)
void edge_out(const __bf16* __restrict__ P, const int* __restrict__ src,
              const int* __restrict__ dst,
              const float* __restrict__ w3, const float* __restrict__ b3,
              const float* __restrict__ gamma, const float* __restrict__ beta,
              float* __restrict__ out) {
    const int tid = threadIdx.x;
    const int g   = tid >> 5;          // 8 groups of 32 lanes
    const int j   = tid & 31;          // lane in group; covers h = j*8..j*8+8
    const int e0  = blockIdx.x * 128 + g * 16;   // 16 edges per group

    const float b3v = b3[0];
    const float4* pg = (const float4*)(gamma + j * 8);
    const float4* pt = (const float4*)(beta  + j * 8);
    const float4* pw = (const float4*)(w3    + j * 8);

    #pragma unroll 2
    for (int i = 0; i < 16; ++i) {
        int e  = e0 + i;
        int ec = e < EE ? e : EE - 1;
        int s = src[ec], d = dst[ec];    // uniform in group -> L1 broadcast

        uint4 av = *(const uint4*)(P + (size_t)s * 512 + j * 8);
        uint4 cv = *(const uint4*)(P + (size_t)d * 512 + 256 + j * 8);
        bf16x8 a = __builtin_bit_cast(bf16x8, av);
        bf16x8 c = __builtin_bit_cast(bf16x8, cv);

        float x[8];
        #pragma unroll
        for (int z = 0; z < 8; ++z)
            x[z] = (float)a[z] + (float)c[z];      // b1 pre-folded into P

        float sum = 0.f, sq = 0.f;
        #pragma unroll
        for (int z = 0; z < 8; ++z) {
            sum += x[z];
            sq   = fmaf(x[z], x[z], sq);
        }
        #pragma unroll
        for (int m = 1; m < 32; m <<= 1) {
            sum += __shfl_xor(sum, m, 32);
            sq  += __shfl_xor(sq,  m, 32);
        }
        float mu = sum * (1.0f / 256.0f);
        float rs = rsqrtf(sq * (1.0f / 256.0f) - mu * mu + LN_EPS);

        float4 g0 = pg[0], g1 = pg[1];
        float4 t0 = pt[0], t1 = pt[1];
        float4 w0 = pw[0], w1 = pw[1];
        float gvv[8] = {g0.x, g0.y, g0.z, g0.w, g1.x, g1.y, g1.z, g1.w};
        float tvv[8] = {t0.x, t0.y, t0.z, t0.w, t1.x, t1.y, t1.z, t1.w};
        float wvv[8] = {w0.x, w0.y, w0.z, w0.w, w1.x, w1.y, w1.z, w1.w};

        float dot = 0.f;
        #pragma unroll
        for (int z = 0; z < 8; ++z) {
            float y = fmaxf((x[z] - mu) * rs * gvv[z] + tvv[z], 0.f);
            dot = fmaf(y, wvv[z], dot);
        }
        #pragma unroll
        for (int m = 1; m < 32; m <<= 1) dot += __shfl_xor(dot, m, 32);

        if (j == 0 && e < EE) out[e] = dot + b3v;
    }
}

extern "C" void kernel_launch(void* const* d_in, const int* in_sizes, int n_in,
                              void* d_out, int out_size, void* d_ws, size_t ws_size,
                              hipStream_t stream) {
    const float* h_all  = (const float*)d_in[0];
    const int*   src    = (const int*)  d_in[1];
    const int*   dst    = (const int*)  d_in[2];
    const float* W1     = (const float*)d_in[3];
    const float* b1     = (const float*)d_in[4];
    const float* W3     = (const float*)d_in[5];
    const float* b3     = (const float*)d_in[6];
    const float* gamma2 = (const float*)d_in[7];
    const float* beta2  = (const float*)d_in[8];
    float* out = (float*)d_out;

    __bf16* w2c = (__bf16*)d_ws;                       // 131072 bf16 = 256 KB
    __bf16* P   = w2c + 131072;                        // 50000*512 bf16 = 51.2 MB

    w2_conv<<<64, 256, 0, stream>>>(W1, w2c);
    node_proj<<<(NN + 127) / 128, 256, 0, stream>>>(h_all, w2c, b1, P);
    edge_out<<<(EE + 127) / 128, 256, 0, stream>>>(P, src, dst, W3, b3,
                                                   gamma2, beta2, out);
}

// Round 12
// 193.817 us; speedup vs baseline: 2.3377x; 1.0467x over previous
//
#include <hip/hip_runtime.h>
#include <hip/hip_bf16.h>

#define LL 4
#define NN 50000
#define DD 64
#define EE 500000
#define HID 256
#define KDIM 512
#define LN_EPS 1e-5f

typedef __bf16 bf16x8 __attribute__((ext_vector_type(8)));
typedef float f32x16 __attribute__((ext_vector_type(16)));

__device__ __forceinline__ void async16(const void* g, void* l) {
    __builtin_amdgcn_global_load_lds(
        (const __attribute__((address_space(1))) void*)g,
        (__attribute__((address_space(3))) void*)l, 16, 0, 0);
}

// ---------- kernel 1: W1 (256x512 f32) -> W'' (512 out-cols x 256 K) bf16 ----
// Out-col j<256: Ps row j (src cols of W1); j>=256: Pd row j-256 (dst cols).
// K index k means feature (l = k>>6, d = k&63) -> W1 col l*128 + 64*(j>=256) + d.
// Chunk layout: w2c[(b*512 + j)*8 + z], chunk b covers k in [8b, 8b+8).
__global__ void w2_conv(const float* __restrict__ w1, __bf16* __restrict__ o) {
    int t = blockIdx.x * 256 + threadIdx.x;                 // 16384 threads
    int j  = t & 511;
    int b  = t >> 9;              // [0,32)
    int k0 = (b >> 1) * 16 + (b & 1) * 8;                   // == 8*b
    int r  = j & 255;
    int col = (k0 >> 6) * 128 + ((j >> 8) ? 64 : 0) + (k0 & 63);
    const float4* p = (const float4*)(w1 + r * KDIM + col);
    float4 va = p[0];
    float4 vb = p[1];
    bf16x8 v;
    v[0] = (__bf16)va.x; v[1] = (__bf16)va.y; v[2] = (__bf16)va.z; v[3] = (__bf16)va.w;
    v[4] = (__bf16)vb.x; v[5] = (__bf16)vb.y; v[6] = (__bf16)vb.z; v[7] = (__bf16)vb.w;
    *(bf16x8*)(o + (size_t)t * 8) = v;
}

// ---------- kernel 2: FUSED tanh + node projections (R6 structure) ----------
// P[n][512] = [Ps | Pd+b1] (bf16). Grid 391. Measured-best node_proj
// (totals 195.1/194.4 in R6/R8). Unchanged.
__global__ __launch_bounds__(256, 2)
void node_proj(const float* __restrict__ h, const __bf16* __restrict__ w2c,
               const float* __restrict__ b1, __bf16* __restrict__ P) {
    __shared__ __align__(16) char smem[65536];
    __bf16* Bs  = (__bf16*)smem;      // 64 KB B slice during MFMA
    __bf16* Cs2 = (__bf16*)smem;      // 32 KB bf16 C bounce (phase-separated)

    const int tid  = threadIdx.x;
    const int wave = tid >> 6;
    const int lane = tid & 63;
    const int h32  = lane >> 5;
    const int c32  = lane & 31;
    const int n00  = blockIdx.x * 128;

    // stage B slice for cb=0: 16 x 2KB linear pieces
    #pragma unroll
    for (int it = 0; it < 16; ++it) {
        int o = it * 2048 + tid * 8;   // elem offset within 32768-elem slice
        async16(w2c + (size_t)(o >> 10) * 4096 + (o & 1023), Bs + o);
    }

    // A fragments: read h (f32) once, tanh+scale+convert in registers.
    int node = n00 + wave * 32 + c32;
    if (node >= NN) node = NN - 1;
    bf16x8 af[16];
    #pragma unroll
    for (int u = 0; u < 16; ++u) {
        int l = u >> 2;
        float imp = (float)(l + 1) * 0.1f;
        const float* p = h + (size_t)l * (NN * DD) + node * DD
                       + (u & 3) * 16 + h32 * 8;
        float4 va = *(const float4*)p;
        float4 vb = *(const float4*)(p + 4);
        float xv[8] = {va.x, va.y, va.z, va.w, vb.x, vb.y, vb.z, vb.w};
        #pragma unroll
        for (int z = 0; z < 8; ++z) {
            float e2 = __expf(2.0f * (imp * xv[z]));
            af[u][z] = (__bf16)(1.0f - 2.0f / (e2 + 1.0f));
        }
    }

    for (int cb = 0; cb < 4; ++cb) {
        __syncthreads();               // B(cb) resident; LDS free of prior phase

        f32x16 acc[4];
        #pragma unroll
        for (int nt = 0; nt < 4; ++nt) acc[nt] = (f32x16)(0.f);

        #pragma unroll
        for (int u = 0; u < 16; ++u) {
            const __bf16* Bk = Bs + (u * 2 + h32) * 1024 + c32 * 8;
            #pragma unroll
            for (int nt = 0; nt < 4; ++nt) {
                bf16x8 bf = *(const bf16x8*)(Bk + nt * 256);
                acc[nt] = __builtin_amdgcn_mfma_f32_32x32x16_bf16(af[u], bf, acc[nt], 0, 0, 0);
            }
        }
        __syncthreads();               // all waves done reading Bs

        float b1v[4];
        #pragma unroll
        for (int nt = 0; nt < 4; ++nt)
            b1v[nt] = (cb >= 2) ? b1[(cb - 2) * 128 + nt * 32 + c32] : 0.f;

        // bounce C (bf16) through LDS for coalesced row stores
        // C/D 32x32 layout: col = c32, row = (r&3) + 8*(r>>2) + 4*h32
        #pragma unroll
        for (int nt = 0; nt < 4; ++nt) {
            #pragma unroll
            for (int r = 0; r < 16; ++r) {
                int nl = wave * 32 + (r & 3) + 8 * (r >> 2) + 4 * h32;
                Cs2[nl * 128 + nt * 32 + c32] = (__bf16)(acc[nt][r] + b1v[nt]);
            }
        }
        __syncthreads();               // Cs2 complete

        #pragma unroll
        for (int it = 0; it < 8; ++it) {
            int o  = it * 2048 + tid * 8;
            int nl = o >> 7;
            int n  = n00 + nl;
            if (n < NN)
                *(bf16x8*)(P + (size_t)n * 512 + cb * 128 + (o & 127)) =
                    *(const bf16x8*)(Cs2 + o);
        }

        if (cb < 3) {
            __syncthreads();           // store-side LDS reads done before overwrite
            #pragma unroll
            for (int it = 0; it < 16; ++it) {
                int o = it * 2048 + tid * 8;
                async16(w2c + (size_t)(o >> 10) * 4096 + (cb + 1) * 1024 + (o & 1023),
                        Bs + o);
            }
        }
    }
}

// ---------- kernel 3: per-edge gather + LN + ReLU + dot (R8-exact) ----------
// FINAL configuration, byte-identical to the R8 measured-best build
// (70.3-70.7 us). Closed evidence set:
//   R8  16-lane groups + 3-slot ILP, occ 36%          -> 70.3  (best)
//   R11 32-lane slim, occ 74%, clean counters          -> 80.0  (TLP not the
//        constraint: 2x resident waves, same traffic, slower)
//   R9/R10 bound=8/6 on this body -> VGPR cap 32/40 -> spill -> 230-333
//   R4  src-bucket sorted: edge_out ~55 but sort cost +121 -> net loss
// Conclusion: random-512B-granule service rate (~3.45 TB/s L2-fill,
// ~7.3 TB/s demand-level) is the ceiling; only locality moves it and no
// sort pays for itself. Keep bound=3.
__global__ __launch_bounds__(256, 3)
void edge_out(const __bf16* __restrict__ P, const int* __restrict__ src,
              const int* __restrict__ dst,
              const float* __restrict__ w3, const float* __restrict__ b3,
              const float* __restrict__ gamma, const float* __restrict__ beta,
              float* __restrict__ out) {
    const int tid = threadIdx.x;
    const int g   = tid >> 4;
    const int j   = tid & 15;

    float gv[16], btv[16], wv[16];
    {
        const float4* pg = (const float4*)(gamma + j * 16);
        const float4* pt = (const float4*)(beta + j * 16);
        const float4* pw = (const float4*)(w3 + j * 16);
        #pragma unroll
        for (int z = 0; z < 4; ++z) {
            float4 vg = pg[z], vt = pt[z], vw = pw[z];
            gv [z*4+0] = vg.x; gv [z*4+1] = vg.y; gv [z*4+2] = vg.z; gv [z*4+3] = vg.w;
            btv[z*4+0] = vt.x; btv[z*4+1] = vt.y; btv[z*4+2] = vt.z; btv[z*4+3] = vt.w;
            wv [z*4+0] = vw.x; wv [z*4+1] = vw.y; wv [z*4+2] = vw.z; wv [z*4+3] = vw.w;
        }
    }
    const float b3v = b3[0];
    const int e0 = blockIdx.x * 128 + g * 8;

    // preload this group's 8 src + 8 dst indices (lane j&7 holds edge e0+(j&7))
    int ep = e0 + (j & 7);
    if (ep >= EE) ep = EE - 1;
    const int sj = src[ep];
    const int dj = dst[ep];

    uint4 s0[3], s1[3], d0[3], d1[3];   // 3-slot rotation, static indices

    #pragma unroll
    for (int i = 0; i < 2; ++i) {       // prologue: edges 0 and 1 in flight
        int s = __shfl(sj, i, 16);
        int d = __shfl(dj, i, 16);
        const uint4* ps = (const uint4*)(P + (size_t)s * 512 + j * 16);
        const uint4* pd = (const uint4*)(P + (size_t)d * 512 + 256 + j * 16);
        s0[i] = ps[0]; s1[i] = ps[1]; d0[i] = pd[0]; d1[i] = pd[1];
    }

    #pragma unroll
    for (int i = 0; i < 8; ++i) {
        if (i + 2 < 8) {                // prefetch edge i+2
            const int slot = (i + 2) % 3;
            int s = __shfl(sj, i + 2, 16);
            int d = __shfl(dj, i + 2, 16);
            const uint4* ps = (const uint4*)(P + (size_t)s * 512 + j * 16);
            const uint4* pd = (const uint4*)(P + (size_t)d * 512 + 256 + j * 16);
            s0[slot] = ps[0]; s1[slot] = ps[1]; d0[slot] = pd[0]; d1[slot] = pd[1];
        }
        const int cs = i % 3;
        bf16x8 a0 = __builtin_bit_cast(bf16x8, s0[cs]);
        bf16x8 a1 = __builtin_bit_cast(bf16x8, s1[cs]);
        bf16x8 c0 = __builtin_bit_cast(bf16x8, d0[cs]);
        bf16x8 c1 = __builtin_bit_cast(bf16x8, d1[cs]);
        float x[16];
        #pragma unroll
        for (int z = 0; z < 8; ++z) {
            x[z]     = (float)a0[z] + (float)c0[z];     // b1 pre-folded into P
            x[z + 8] = (float)a1[z] + (float)c1[z];
        }
        float sum = 0.f, sq = 0.f;
        #pragma unroll
        for (int z = 0; z < 16; ++z) {
            sum += x[z];
            sq   = fmaf(x[z], x[z], sq);
        }
        #pragma unroll
        for (int m = 1; m < 16; m <<= 1) {
            sum += __shfl_xor(sum, m);
            sq  += __shfl_xor(sq,  m);
        }
        float mu = sum * (1.0f / 256.0f);
        float rs = rsqrtf(sq * (1.0f / 256.0f) - mu * mu + LN_EPS);
        float dot = 0.f;
        #pragma unroll
        for (int z = 0; z < 16; ++z) {
            float y = fmaxf((x[z] - mu) * rs * gv[z] + btv[z], 0.f);
            dot = fmaf(y, wv[z], dot);
        }
        #pragma unroll
        for (int m = 1; m < 16; m <<= 1) dot += __shfl_xor(dot, m);
        int e = e0 + i;
        if (j == 0 && e < EE) out[e] = dot + b3v;
    }

    // keep-alive (matches the measured-best build exactly)
    #pragma unroll
    for (int z = 0; z < 16; ++z)
        asm volatile("" :: "v"(gv[z]), "v"(btv[z]), "v"(wv[z]));
}

extern "C" void kernel_launch(void* const* d_in, const int* in_sizes, int n_in,
                              void* d_out, int out_size, void* d_ws, size_t ws_size,
                              hipStream_t stream) {
    const float* h_all  = (const float*)d_in[0];
    const int*   src    = (const int*)  d_in[1];
    const int*   dst    = (const int*)  d_in[2];
    const float* W1     = (const float*)d_in[3];
    const float* b1     = (const float*)d_in[4];
    const float* W3     = (const float*)d_in[5];
    const float* b3     = (const float*)d_in[6];
    const float* gamma2 = (const float*)d_in[7];
    const float* beta2  = (const float*)d_in[8];
    float* out = (float*)d_out;

    __bf16* w2c = (__bf16*)d_ws;                       // 131072 bf16 = 256 KB
    __bf16* P   = w2c + 131072;                        // 50000*512 bf16 = 51.2 MB

    w2_conv<<<64, 256, 0, stream>>>(W1, w2c);
    node_proj<<<(NN + 127) / 128, 256, 0, stream>>>(h_all, w2c, b1, P);
    edge_out<<<(EE + 127) / 128, 256, 0, stream>>>(P, src, dst, W3, b3,
                                                   gamma2, beta2, out);
}